// Round 3
// baseline (419.304 us; speedup 1.0000x reference)
//
#include <hip/hip_runtime.h>
#include <hip/hip_bf16.h>
#include <math.h>

typedef __hip_bfloat16 bf16;
typedef short short8 __attribute__((ext_vector_type(8)));
typedef float f32x4 __attribute__((ext_vector_type(4)));

__device__ __forceinline__ float b2f(const bf16 v) { return __bfloat162float(v); }
__device__ __forceinline__ bf16 f2b(const float v) { return __float2bfloat16(v); }

// raw-bits bf16 -> f32 (avoids struct round-trips on vector lanes)
__device__ __forceinline__ float bits2f(short s) {
  unsigned u = ((unsigned)(unsigned short)s) << 16;
  float f;
  __builtin_memcpy(&f, &u, 4);
  return f;
}
__device__ __forceinline__ short f2bits(float f) {
  bf16 b = f2b(f);
  short s;
  __builtin_memcpy(&s, &b, 2);
  return s;
}

// dtype-flexible load/store: f32 flag selects float32 vs bfloat16 interpretation
__device__ __forceinline__ float ldsel(const void* p, size_t i, int f32) {
  return f32 ? ((const float*)p)[i] : b2f(((const bf16*)p)[i]);
}
__device__ __forceinline__ void stsel(void* p, size_t i, float v, int f32) {
  if (f32) ((float*)p)[i] = v; else ((bf16*)p)[i] = f2b(v);
}

#define NN 3712          // nodes
#define NE 37120         // edges (without self loops)
#define NG 32            // graphs
#define NREG 116         // nodes per graph
#define MAXDEG 48        // bucket capacity (in-degree ~ Poisson(10); P(>48) ~ 1e-18)

// ---------------- dtype detector ----------------
__global__ __launch_bounds__(256) void k_detect(const void* nf, const void* w0, int* flags) {
  __shared__ int bad[2];
  if (threadIdx.x < 2) bad[threadIdx.x] = 0;
  __syncthreads();
  const bf16* a = (const bf16*)nf;
  const bf16* b = (const bf16*)w0;
  int l0 = 0, l1 = 0;
  for (int i = threadIdx.x; i < 4096; i += 256) {
    float x = b2f(a[i]); if (!(fabsf(x) < 1e4f)) l0++;
    float y = b2f(b[i]); if (!(fabsf(y) < 1e4f)) l1++;
  }
  if (l0) atomicAdd(&bad[0], l0);
  if (l1) atomicAdd(&bad[1], l1);
  __syncthreads();
  if (threadIdx.x == 0) { flags[0] = bad[0] > 0; flags[1] = bad[1] > 0; }
}

// ---------------- utility kernels ----------------
__global__ __launch_bounds__(256) void k_zero(int* __restrict__ p, int n) {
  int i = blockIdx.x * 256 + threadIdx.x;
  if (i < n) p[i] = 0;
}

__global__ __launch_bounds__(256) void k_scatter(const int* __restrict__ src, const int* __restrict__ dst,
                                                 int* __restrict__ cnt, int* __restrict__ bucket, int E) {
  int e = blockIdx.x * 256 + threadIdx.x;
  if (e < E) {
    int d = dst[e], s = src[e];
    if ((unsigned)d < NN && (unsigned)s < NN) {
      int p = atomicAdd(&cnt[d], 1);
      if (p < MAXDEG) bucket[d * MAXDEG + p] = s;
    }
  }
}

// convert (f32|bf16) -> bf16
__global__ __launch_bounds__(256) void k_tobf16(const void* __restrict__ in, bf16* __restrict__ out,
                                                int n, const int* __restrict__ flags, int fidx) {
  int f = flags[fidx];
  int i = blockIdx.x * 256 + threadIdx.x;
  if (i < n) out[i] = f2b(ldsel(in, i, f));
}

// transpose W[K][N] -> Wt[N][K], output bf16. K,N multiples of 32.
__global__ __launch_bounds__(256) void k_transpose(const void* __restrict__ W, bf16* __restrict__ Wt,
                                                   int K, int N, const int* __restrict__ flags) {
  int f = flags[1];
  __shared__ float tile[32][33];
  int tx = threadIdx.x & 31, ty = threadIdx.x >> 5;   // 32 x 8
  int k0 = blockIdx.x * 32, n0 = blockIdx.y * 32;
#pragma unroll
  for (int i = 0; i < 4; ++i)
    tile[ty + i * 8][tx] = ldsel(W, (size_t)(k0 + ty + i * 8) * N + n0 + tx, f);
  __syncthreads();
#pragma unroll
  for (int i = 0; i < 4; ++i)
    Wt[(size_t)(n0 + ty + i * 8) * K + k0 + tx] = f2b(tile[tx][ty + i * 8]);
}

// ---------------- MFMA bf16 NT GEMM: C[MxN] = A[MxK] * Bt[NxK]^T ----------------
// 128x128 tile, BK=32, 4 waves (2x2), each wave 4x4 tiles of 16x16x32 MFMA.
__global__ __launch_bounds__(256) void k_gemm_mfma(const bf16* __restrict__ A, const bf16* __restrict__ Bt,
                                                   bf16* __restrict__ C, int M, int N, int K) {
  __shared__ short As[128 * 40];
  __shared__ short Bs[128 * 40];
  int tid = threadIdx.x;
  int wave = tid >> 6, lane = tid & 63;
  int wr = wave >> 1, wc = wave & 1;
  int quad = lane >> 4, ml = lane & 15;
  int m0 = blockIdx.y * 128, n0 = blockIdx.x * 128;
  f32x4 acc[4][4] = {{{0.f,0.f,0.f,0.f}}};
#pragma unroll
  for (int rt = 0; rt < 4; ++rt)
#pragma unroll
    for (int ct = 0; ct < 4; ++ct)
#pragma unroll
      for (int r = 0; r < 4; ++r) acc[rt][ct][r] = 0.f;

  for (int k0 = 0; k0 < K; k0 += 32) {
    __syncthreads();                       // previous-iter LDS reads done
#pragma unroll
    for (int i = 0; i < 2; ++i) {
      int c = tid + i * 256;               // 512 16B-chunks per operand tile
      int row = c >> 2, kg = (c & 3) * 8;
      *(uint4*)&As[row * 40 + kg] = *(const uint4*)&A[(size_t)(m0 + row) * K + k0 + kg];
      *(uint4*)&Bs[row * 40 + kg] = *(const uint4*)&Bt[(size_t)(n0 + row) * K + k0 + kg];
    }
    __syncthreads();
    short8 af[4], bfr[4];
#pragma unroll
    for (int rt = 0; rt < 4; ++rt)
      af[rt] = *(const short8*)&As[(wr * 64 + rt * 16 + ml) * 40 + quad * 8];
#pragma unroll
    for (int ct = 0; ct < 4; ++ct)
      bfr[ct] = *(const short8*)&Bs[(wc * 64 + ct * 16 + ml) * 40 + quad * 8];
#pragma unroll
    for (int rt = 0; rt < 4; ++rt)
#pragma unroll
      for (int ct = 0; ct < 4; ++ct)
        acc[rt][ct] = __builtin_amdgcn_mfma_f32_16x16x32_bf16(af[rt], bfr[ct], acc[rt][ct], 0, 0, 0);
  }
  // C/D layout (verified m89/m91): col = lane&15, row = quad*4 + reg
#pragma unroll
  for (int rt = 0; rt < 4; ++rt)
#pragma unroll
    for (int ct = 0; ct < 4; ++ct)
#pragma unroll
      for (int r = 0; r < 4; ++r) {
        int grow = m0 + wr * 64 + rt * 16 + quad * 4 + r;
        int gcol = n0 + wc * 64 + ct * 16 + ml;
        C[(size_t)grow * N + gcol] = f2b(acc[rt][ct][r]);
      }
}

// ---------------- attention coefficients al/ar: (N,8) ----------------
// Thread t owns 8 contiguous dims (short8 load); per-head group reduce via shfl_xor.
__global__ __launch_bounds__(256) void k_attn(const bf16* __restrict__ H, const void* __restrict__ a_s,
                                              const void* __restrict__ a_d, float* __restrict__ al,
                                              float* __restrict__ ar, int C, const int* __restrict__ flags) {
  int wF = flags[1];
  int n = blockIdx.x;
  int t = threadIdx.x;
  int D = 8 * C;
  int i0 = t * 8;
  if (i0 >= D) return;                     // no barriers below
  union { short8 v; short s[8]; } u;
  u.v = *(const short8*)&H[(size_t)n * D + i0];
  float ps = 0.f, pd = 0.f;
#pragma unroll
  for (int j = 0; j < 8; ++j) {
    float h = bits2f(u.s[j]);
    ps = fmaf(h, ldsel(a_s, i0 + j, wF), ps);
    pd = fmaf(h, ldsel(a_d, i0 + j, wF), pd);
  }
  int G = C >> 3;                          // lanes per head group: 32/16/8 (aligned pow2, within-wave)
  for (int off = G >> 1; off; off >>= 1) {
    ps += __shfl_xor(ps, off);
    pd += __shfl_xor(pd, off);
  }
  if ((t & (G - 1)) == 0) {
    int hd = i0 / C;
    al[n * 8 + hd] = ps;
    ar[n * 8 + hd] = pd;
  }
}

// ---------------- per-dst softmax + aggregation + bias + ELU + LayerNorm ----------------
// One block per dst node. XCD-bijective swizzle keeps each graph's H-slice in one
// XCD's L2 (4 graphs x 475KB < 4MB). All H traffic is short8 (16B/lane).
__global__ __launch_bounds__(256) void k_agg(const bf16* __restrict__ H, const float* __restrict__ al,
                                             const float* __restrict__ ar, const int* __restrict__ cnt,
                                             const int* __restrict__ bucket, const void* __restrict__ bias,
                                             const void* __restrict__ ls, const void* __restrict__ lb,
                                             bf16* __restrict__ Xout, int C, int concat,
                                             const int* __restrict__ flags) {
  int wF = flags[1];
  // bijective node swizzle: XCD x = bid&7 handles graphs {x, x+8, x+16, x+24}
  int bid = blockIdx.x;
  int x = bid & 7, jj = bid >> 3;                       // jj in [0,464)
  int d = (x + ((jj / NREG) << 3)) * NREG + (jj % NREG);
  int t = threadIdx.x;
  int lane = t & 63, wave = t >> 6;
  int D = 8 * C;
  __shared__ int sid[MAXDEG + 1];
  __shared__ float w[8][MAXDEG + 2];
  __shared__ float vals[512];                           // mean (non-concat) path only
  __shared__ float r1[4], r2[4];
  __shared__ float sMu, sRs;

  int deg = cnt[d]; deg = deg > MAXDEG ? MAXDEG : deg;
  if (t < deg) sid[t] = bucket[d * MAXDEG + t];
  if (t == deg) sid[deg] = d;                           // self loop (PyG appends it always)
  __syncthreads();
  int total = deg + 1;

  // per-head segment softmax: 8 heads x 8 lanes (wave 0)
  if (t < 64) {
    int hd = t >> 3, le = t & 7;
    float ard = ar[d * 8 + hd];
    float m = -1e30f;
    for (int e = le; e < total; e += 8) {
      float lg = al[sid[e] * 8 + hd] + ard;
      lg = lg > 0.f ? lg : 0.2f * lg;                   // leaky_relu(0.2)
      w[hd][e] = lg;
      m = fmaxf(m, lg);
    }
#pragma unroll
    for (int off = 4; off; off >>= 1) m = fmaxf(m, __shfl_xor(m, off));
    float den = 0.f;
    for (int e = le; e < total; e += 8) { float xv = expf(w[hd][e] - m); w[hd][e] = xv; den += xv; }
#pragma unroll
    for (int off = 4; off; off >>= 1) den += __shfl_xor(den, off);
    float inv = 1.f / den;
    for (int e = le; e < total; e += 8) w[hd][e] *= inv;
  }
  __syncthreads();

  // vectorized gather-accumulate: thread t owns dims [t*8, t*8+8) (one head each)
  int i0 = t * 8;
  float acc[8] = {0.f, 0.f, 0.f, 0.f, 0.f, 0.f, 0.f, 0.f};
  if (i0 < D) {
    int hd = i0 / C;
    const bf16* __restrict__ Hp = H + i0;
    for (int e = 0; e < total; ++e) {
      union { short8 v; short s[8]; } u;
      u.v = *(const short8*)&Hp[(size_t)sid[e] * D];
      float we = w[hd][e];
#pragma unroll
      for (int j = 0; j < 8; ++j) acc[j] = fmaf(we, bits2f(u.s[j]), acc[j]);
    }
  }

  if (concat) {
    float v[8];
    float s1 = 0.f, s2 = 0.f;
    if (i0 < D) {
#pragma unroll
      for (int j = 0; j < 8; ++j) {
        float vv = acc[j] + ldsel(bias, i0 + j, wF);
        vv = vv > 0.f ? vv : expf(vv) - 1.f;            // ELU
        v[j] = vv; s1 += vv; s2 += vv * vv;
      }
    }
#pragma unroll
    for (int off = 32; off; off >>= 1) { s1 += __shfl_down(s1, off); s2 += __shfl_down(s2, off); }
    if (lane == 0) { r1[wave] = s1; r2[wave] = s2; }
    __syncthreads();
    if (t == 0) {
      float S1 = r1[0] + r1[1] + r1[2] + r1[3];
      float S2 = r2[0] + r2[1] + r2[2] + r2[3];
      float mu = S1 / D;
      sMu = mu; sRs = rsqrtf(S2 / D - mu * mu + 1e-5f);
    }
    __syncthreads();
    if (i0 < D) {
      union { short8 v; short s[8]; } ou;
#pragma unroll
      for (int j = 0; j < 8; ++j)
        ou.s[j] = f2bits((v[j] - sMu) * sRs * ldsel(ls, i0 + j, wF) + ldsel(lb, i0 + j, wF));
      *(short8*)&Xout[(size_t)d * D + i0] = ou.v;
    }
  } else {
    if (i0 < D) {
#pragma unroll
      for (int j = 0; j < 8; ++j) vals[i0 + j] = acc[j];
    }
    __syncthreads();
    if (t < 64) {   // wave 0: mean over 8 heads -> 64 dims, ELU, LN over 64
      float v = 0.f;
#pragma unroll
      for (int h = 0; h < 8; ++h) v += vals[h * 64 + t];
      v = v * 0.125f + ldsel(bias, t, wF);
      v = v > 0.f ? v : expf(v) - 1.f;
      float s1 = v, s2 = v * v;
#pragma unroll
      for (int off = 32; off; off >>= 1) { s1 += __shfl_xor(s1, off); s2 += __shfl_xor(s2, off); }
      float mu = s1 * (1.f / 64.f);
      float var = s2 * (1.f / 64.f) - mu * mu;
      float rs = rsqrtf(var + 1e-5f);
      Xout[(size_t)d * 64 + t] = f2b((v - mu) * rs * ldsel(ls, t, wF) + ldsel(lb, t, wF));
    }
  }
}

// ---------------- projection (64->256) + LN + GELU(erf) + q ----------------
__global__ __launch_bounds__(256) void k_proj(const bf16* __restrict__ X3, const void* __restrict__ wp,
                                              const void* __restrict__ bp, const void* __restrict__ lsp,
                                              const void* __restrict__ lbp, const void* __restrict__ wq,
                                              const void* __restrict__ bq,
                                              float* __restrict__ q, void* __restrict__ dout,
                                              const int* __restrict__ flags) {
  int wF = flags[1], xF = flags[0];
  int n = blockIdx.x, t = threadIdx.x;
  int lane = t & 63, wave = t >> 6;
  __shared__ float xs[64];
  __shared__ float r1[4], r2[4];
  __shared__ float sMu, sRs;
  if (t < 64) xs[t] = b2f(X3[n * 64 + t]);
  __syncthreads();
  float y = ldsel(bp, t, wF);
#pragma unroll 8
  for (int k = 0; k < 64; ++k) y = fmaf(xs[k], ldsel(wp, k * 256 + t, wF), y);
  float s1 = y, s2 = y * y;
#pragma unroll
  for (int off = 32; off; off >>= 1) { s1 += __shfl_down(s1, off); s2 += __shfl_down(s2, off); }
  if (lane == 0) { r1[wave] = s1; r2[wave] = s2; }
  __syncthreads();
  if (t == 0) {
    float S1 = r1[0] + r1[1] + r1[2] + r1[3];
    float S2 = r2[0] + r2[1] + r2[2] + r2[3];
    float mu = S1 / 256.f;
    sMu = mu; sRs = rsqrtf(S2 / 256.f - mu * mu + 1e-5f);
  }
  __syncthreads();
  float v = (y - sMu) * sRs * ldsel(lsp, t, wF) + ldsel(lbp, t, wF);
  float g = 0.5f * v * (1.f + erff(v * 0.70710678118654752f));   // exact GELU
  stsel(dout, (size_t)NG * 256 + (size_t)n * 256 + t, g, xF);    // node_out
  float qv = g * ldsel(wq, t, wF);
#pragma unroll
  for (int off = 32; off; off >>= 1) qv += __shfl_down(qv, off);
  if (lane == 0) r1[wave] = qv;
  __syncthreads();
  if (t == 0) q[n] = r1[0] + r1[1] + r1[2] + r1[3] + ldsel(bq, 0, wF);
}

// ---------------- attention pooling per graph ----------------
__global__ __launch_bounds__(256) void k_pool(void* __restrict__ dout, const float* __restrict__ q,
                                              const int* __restrict__ flags) {
  int xF = flags[0];
  int b = blockIdx.x, t = threadIdx.x;
  __shared__ float es[NREG];
  __shared__ float sDen;
  if (t < NREG) es[t] = q[b * NREG + t];
  __syncthreads();
  if (t == 0) {
    float m = -1e30f;
    for (int i = 0; i < NREG; ++i) m = fmaxf(m, es[i]);
    float den = 0.f;
    for (int i = 0; i < NREG; ++i) { float e = expf(es[i] - m); es[i] = e; den += e; }
    sDen = den;
  }
  __syncthreads();
  float acc = 0.f;
  for (int i = 0; i < NREG; ++i)
    acc = fmaf(es[i], ldsel(dout, (size_t)NG * 256 + (size_t)(b * NREG + i) * 256 + t, xF), acc);
  stsel(dout, (size_t)b * 256 + t, acc / sDen, xF);
}

// ---------------- launcher ----------------
extern "C" void kernel_launch(void* const* d_in, const int* in_sizes, int n_in,
                              void* d_out, int out_size, void* d_ws, size_t ws_size,
                              hipStream_t stream) {
  const void* nf  = d_in[0];
  const int* src  = (const int*)d_in[1];
  const int* dst  = (const int*)d_in[2];
  const void *w0 = d_in[4],  *b0 = d_in[5],  *as0 = d_in[6], *ad0 = d_in[7],  *ls0 = d_in[8],  *lb0 = d_in[9];
  const void *w1 = d_in[10], *b1 = d_in[11], *as1 = d_in[12], *ad1 = d_in[13], *ls1 = d_in[14], *lb1 = d_in[15];
  const void *w2 = d_in[16], *b2 = d_in[17], *as2 = d_in[18], *ad2 = d_in[19], *ls2 = d_in[20], *lb2 = d_in[21];
  const void *wp = d_in[22], *bp = d_in[23], *lsp = d_in[24], *lbp = d_in[25], *wq = d_in[26], *bq = d_in[27];

  // workspace layout — TOTAL ~31.4 MB (same as passing R2 layout)
  int* flags  = (int*)d_ws;                       // 4 ints (16 B)
  float* al   = (float*)(flags + 4);              // NN*8 f32
  float* ar   = al + NN * 8;
  int* cnt    = (int*)(ar + NN * 8);              // NN
  int* bucket = cnt + NN;                         // NN*MAXDEG
  float* q    = (float*)(bucket + NN * MAXDEG);   // NN f32
  bf16* X     = (bf16*)(q + NN);                  // NN*2048 bf16 (16B-aligned)
  bf16* Hb    = X + (size_t)NN * 2048;            // NN*2048 bf16

  // dead-region reuse for bf16 staging buffers:
  bf16* X0  = X;                          // NN*256 bf16 input copy (dead after gemm0)
  bf16* wt0 = X + (1 << 20);              // 2048*256  (dead after gemm0; agg0 then overwrites X)
  bf16* wt1 = Hb + (size_t)NN * 1024;     // 1024*2048 in upper half of Hb (gemm1 writes lower half)
  bf16* wt2 = Hb + (size_t)NN * 512;      // 512*1024  above gemm2's output region

  // stage 0: dtype detect, edge buckets, input conversion
  k_detect<<<1, 256, 0, stream>>>(nf, w0, flags);
  k_zero<<<(NN + 255) / 256, 256, 0, stream>>>(cnt, NN);
  k_scatter<<<(NE + 255) / 256, 256, 0, stream>>>(src, dst, cnt, bucket, NE);
  k_tobf16<<<(NN * 256 + 255) / 256, 256, 0, stream>>>(nf, X0, NN * 256, flags, 0);

  // layer 0: 256 -> 8x256 concat (2048)
  k_transpose<<<dim3(256 / 32, 2048 / 32), 256, 0, stream>>>(w0, wt0, 256, 2048, flags);
  k_gemm_mfma<<<dim3(2048 / 128, NN / 128), 256, 0, stream>>>(X0, wt0, Hb, NN, 2048, 256);
  k_attn<<<NN, 256, 0, stream>>>(Hb, as0, ad0, al, ar, 256, flags);
  k_agg<<<NN, 256, 0, stream>>>(Hb, al, ar, cnt, bucket, b0, ls0, lb0, X, 256, 1, flags);

  // layer 1: 2048 -> 8x128 concat (1024)
  k_transpose<<<dim3(2048 / 32, 1024 / 32), 256, 0, stream>>>(w1, wt1, 2048, 1024, flags);
  k_gemm_mfma<<<dim3(1024 / 128, NN / 128), 256, 0, stream>>>(X, wt1, Hb, NN, 1024, 2048);
  k_attn<<<NN, 256, 0, stream>>>(Hb, as1, ad1, al, ar, 128, flags);
  k_agg<<<NN, 256, 0, stream>>>(Hb, al, ar, cnt, bucket, b1, ls1, lb1, X, 128, 1, flags);

  // layer 2: 1024 -> 8x64 mean (64)
  k_transpose<<<dim3(1024 / 32, 512 / 32), 256, 0, stream>>>(w2, wt2, 1024, 512, flags);
  k_gemm_mfma<<<dim3(512 / 128, NN / 128), 256, 0, stream>>>(X, wt2, Hb, NN, 512, 1024);
  k_attn<<<NN, 256, 0, stream>>>(Hb, as2, ad2, al, ar, 64, flags);
  k_agg<<<NN, 256, 0, stream>>>(Hb, al, ar, cnt, bucket, b2, ls2, lb2, X, 64, 0, flags);

  // projection + GELU + q, then pooling (node_out lives in d_out)
  k_proj<<<NN, 256, 0, stream>>>(X, wp, bp, lsp, lbp, wq, bq, q, d_out, flags);
  k_pool<<<NG, 256, 0, stream>>>(d_out, q, flags);
}

// Round 4
// 387.150 us; speedup vs baseline: 1.0831x; 1.0831x over previous
//
#include <hip/hip_runtime.h>
#include <hip/hip_bf16.h>
#include <math.h>

typedef __hip_bfloat16 bf16;
typedef short short8 __attribute__((ext_vector_type(8)));
typedef float f32x4 __attribute__((ext_vector_type(4)));

__device__ __forceinline__ float b2f(const bf16 v) { return __bfloat162float(v); }
__device__ __forceinline__ bf16 f2b(const float v) { return __float2bfloat16(v); }

// raw-bits bf16 -> f32 (avoids struct round-trips on vector lanes)
__device__ __forceinline__ float bits2f(short s) {
  unsigned u = ((unsigned)(unsigned short)s) << 16;
  float f;
  __builtin_memcpy(&f, &u, 4);
  return f;
}
__device__ __forceinline__ short f2bits(float f) {
  bf16 b = f2b(f);
  short s;
  __builtin_memcpy(&s, &b, 2);
  return s;
}

// dtype-flexible load/store: f32 flag selects float32 vs bfloat16 interpretation
__device__ __forceinline__ float ldsel(const void* p, size_t i, int f32) {
  return f32 ? ((const float*)p)[i] : b2f(((const bf16*)p)[i]);
}
__device__ __forceinline__ void stsel(void* p, size_t i, float v, int f32) {
  if (f32) ((float*)p)[i] = v; else ((bf16*)p)[i] = f2b(v);
}

#define NN 3712          // nodes
#define NE 37120         // edges (without self loops)
#define NG 32            // graphs
#define NREG 116         // nodes per graph
#define MAXDEG 48        // bucket capacity (in-degree ~ Poisson(10); P(>48) ~ 1e-18)

// ---------------- dtype detector ----------------
__global__ __launch_bounds__(256) void k_detect(const void* nf, const void* w0, int* flags) {
  __shared__ int bad[2];
  if (threadIdx.x < 2) bad[threadIdx.x] = 0;
  __syncthreads();
  const bf16* a = (const bf16*)nf;
  const bf16* b = (const bf16*)w0;
  int l0 = 0, l1 = 0;
  for (int i = threadIdx.x; i < 4096; i += 256) {
    float x = b2f(a[i]); if (!(fabsf(x) < 1e4f)) l0++;
    float y = b2f(b[i]); if (!(fabsf(y) < 1e4f)) l1++;
  }
  if (l0) atomicAdd(&bad[0], l0);
  if (l1) atomicAdd(&bad[1], l1);
  __syncthreads();
  if (threadIdx.x == 0) { flags[0] = bad[0] > 0; flags[1] = bad[1] > 0; }
}

// ---------------- utility kernels ----------------
__global__ __launch_bounds__(256) void k_zero(int* __restrict__ p, int n) {
  int i = blockIdx.x * 256 + threadIdx.x;
  if (i < n) p[i] = 0;
}

__global__ __launch_bounds__(256) void k_scatter(const int* __restrict__ src, const int* __restrict__ dst,
                                                 int* __restrict__ cnt, int* __restrict__ bucket, int E) {
  int e = blockIdx.x * 256 + threadIdx.x;
  if (e < E) {
    int d = dst[e], s = src[e];
    if ((unsigned)d < NN && (unsigned)s < NN) {
      int p = atomicAdd(&cnt[d], 1);
      if (p < MAXDEG) bucket[d * MAXDEG + p] = s;
    }
  }
}

// convert (f32|bf16) -> bf16
__global__ __launch_bounds__(256) void k_tobf16(const void* __restrict__ in, bf16* __restrict__ out,
                                                int n, const int* __restrict__ flags, int fidx) {
  int f = flags[fidx];
  int i = blockIdx.x * 256 + threadIdx.x;
  if (i < n) out[i] = f2b(ldsel(in, i, f));
}

// transpose W[K][N] -> Wt[N][K], output bf16. K,N multiples of 32.
__global__ __launch_bounds__(256) void k_transpose(const void* __restrict__ W, bf16* __restrict__ Wt,
                                                   int K, int N, const int* __restrict__ flags) {
  int f = flags[1];
  __shared__ float tile[32][33];
  int tx = threadIdx.x & 31, ty = threadIdx.x >> 5;   // 32 x 8
  int k0 = blockIdx.x * 32, n0 = blockIdx.y * 32;
#pragma unroll
  for (int i = 0; i < 4; ++i)
    tile[ty + i * 8][tx] = ldsel(W, (size_t)(k0 + ty + i * 8) * N + n0 + tx, f);
  __syncthreads();
#pragma unroll
  for (int i = 0; i < 4; ++i)
    Wt[(size_t)(n0 + ty + i * 8) * K + k0 + tx] = f2b(tile[tx][ty + i * 8]);
}

// ---------------- MFMA bf16 NT GEMM: C[MxN] = A[MxK] * Bt[NxK]^T ----------------
// 64x64 tile, BK=64, 4 waves (2x2), each wave 2x2 tiles of 16x16x32 MFMA over 2 k-slices.
// Rationale (R3 counters): 128^2 tiles gave only 232 blocks for 256 CUs -> Occupancy 9%,
// MfmaUtil 9% -> latency-bound. 64^2 quadruples block count (layer-1: 928 -> ~3.6
// blocks/CU, ~14 waves/CU) so resident blocks hide each other's global-load latency.
// LDS rows padded to 72 shorts (144 B = 9x16B): aligned uint4, 2-way bank alias (free).
// 1-D grid + bijective XCD chunk-swizzle: blocks sharing an A-row-panel land on one XCD L2.
__global__ __launch_bounds__(256) void k_gemm_mfma(const bf16* __restrict__ A, const bf16* __restrict__ Bt,
                                                   bf16* __restrict__ C, int M, int N, int K) {
  __shared__ short As[64 * 72];
  __shared__ short Bs[64 * 72];
  int tid = threadIdx.x;
  int wave = tid >> 6, lane = tid & 63;
  int wr = wave >> 1, wc = wave & 1;
  int quad = lane >> 4, ml = lane & 15;

  int nbx = N >> 6;
  int total = gridDim.x;
  int id = blockIdx.x;
  // XCD-bijective chunk swizzle (valid when total % 8 == 0; all our grids are)
  int tile = ((total & 7) == 0) ? ((id & 7) * (total >> 3) + (id >> 3)) : id;
  int n0 = (tile % nbx) << 6;
  int m0 = (tile / nbx) << 6;

  f32x4 acc[2][2];
#pragma unroll
  for (int rt = 0; rt < 2; ++rt)
#pragma unroll
    for (int ct = 0; ct < 2; ++ct)
#pragma unroll
      for (int r = 0; r < 4; ++r) acc[rt][ct][r] = 0.f;

  for (int k0 = 0; k0 < K; k0 += 64) {
    __syncthreads();                       // previous-iter LDS reads done
#pragma unroll
    for (int i = 0; i < 2; ++i) {
      int c = tid + (i << 8);              // 512 16B-chunks per operand tile (64 rows x 8 chunks)
      int row = c >> 3, kg = (c & 7) << 3;
      *(uint4*)&As[row * 72 + kg] = *(const uint4*)&A[(size_t)(m0 + row) * K + k0 + kg];
      *(uint4*)&Bs[row * 72 + kg] = *(const uint4*)&Bt[(size_t)(n0 + row) * K + k0 + kg];
    }
    __syncthreads();
    short8 af[2][2], bfr[2][2];
#pragma unroll
    for (int rt = 0; rt < 2; ++rt)
#pragma unroll
      for (int kk = 0; kk < 2; ++kk)
        af[rt][kk] = *(const short8*)&As[(wr * 32 + rt * 16 + ml) * 72 + kk * 32 + quad * 8];
#pragma unroll
    for (int ct = 0; ct < 2; ++ct)
#pragma unroll
      for (int kk = 0; kk < 2; ++kk)
        bfr[ct][kk] = *(const short8*)&Bs[(wc * 32 + ct * 16 + ml) * 72 + kk * 32 + quad * 8];
#pragma unroll
    for (int rt = 0; rt < 2; ++rt)
#pragma unroll
      for (int ct = 0; ct < 2; ++ct)
#pragma unroll
        for (int kk = 0; kk < 2; ++kk)
          acc[rt][ct] = __builtin_amdgcn_mfma_f32_16x16x32_bf16(af[rt][kk], bfr[ct][kk], acc[rt][ct], 0, 0, 0);
  }
  // C/D layout (verified m89/m91): col = lane&15, row = quad*4 + reg
#pragma unroll
  for (int rt = 0; rt < 2; ++rt)
#pragma unroll
    for (int ct = 0; ct < 2; ++ct)
#pragma unroll
      for (int r = 0; r < 4; ++r) {
        int grow = m0 + wr * 32 + rt * 16 + quad * 4 + r;
        int gcol = n0 + wc * 32 + ct * 16 + ml;
        C[(size_t)grow * N + gcol] = f2b(acc[rt][ct][r]);
      }
}

// ---------------- attention coefficients al/ar: (N,8) ----------------
// Thread t owns 8 contiguous dims (short8 load); per-head group reduce via shfl_xor.
__global__ __launch_bounds__(256) void k_attn(const bf16* __restrict__ H, const void* __restrict__ a_s,
                                              const void* __restrict__ a_d, float* __restrict__ al,
                                              float* __restrict__ ar, int C, const int* __restrict__ flags) {
  int wF = flags[1];
  int n = blockIdx.x;
  int t = threadIdx.x;
  int D = 8 * C;
  int i0 = t * 8;
  if (i0 >= D) return;                     // no barriers below
  union { short8 v; short s[8]; } u;
  u.v = *(const short8*)&H[(size_t)n * D + i0];
  float ps = 0.f, pd = 0.f;
#pragma unroll
  for (int j = 0; j < 8; ++j) {
    float h = bits2f(u.s[j]);
    ps = fmaf(h, ldsel(a_s, i0 + j, wF), ps);
    pd = fmaf(h, ldsel(a_d, i0 + j, wF), pd);
  }
  int G = C >> 3;                          // lanes per head group: 32/16/8 (aligned pow2, within-wave)
  for (int off = G >> 1; off; off >>= 1) {
    ps += __shfl_xor(ps, off);
    pd += __shfl_xor(pd, off);
  }
  if ((t & (G - 1)) == 0) {
    int hd = i0 / C;
    al[n * 8 + hd] = ps;
    ar[n * 8 + hd] = pd;
  }
}

// ---------------- per-dst softmax + aggregation + bias + ELU + LayerNorm ----------------
// One block per dst node. XCD-bijective swizzle keeps each graph's H-slice in one
// XCD's L2 (4 graphs x 475KB < 4MB). All H traffic is short8 (16B/lane).
__global__ __launch_bounds__(256) void k_agg(const bf16* __restrict__ H, const float* __restrict__ al,
                                             const float* __restrict__ ar, const int* __restrict__ cnt,
                                             const int* __restrict__ bucket, const void* __restrict__ bias,
                                             const void* __restrict__ ls, const void* __restrict__ lb,
                                             bf16* __restrict__ Xout, int C, int concat,
                                             const int* __restrict__ flags) {
  int wF = flags[1];
  // bijective node swizzle: XCD x = bid&7 handles graphs {x, x+8, x+16, x+24}
  int bid = blockIdx.x;
  int x = bid & 7, jj = bid >> 3;                       // jj in [0,464)
  int d = (x + ((jj / NREG) << 3)) * NREG + (jj % NREG);
  int t = threadIdx.x;
  int lane = t & 63, wave = t >> 6;
  int D = 8 * C;
  __shared__ int sid[MAXDEG + 1];
  __shared__ float w[8][MAXDEG + 2];
  __shared__ float vals[512];                           // mean (non-concat) path only
  __shared__ float r1[4], r2[4];
  __shared__ float sMu, sRs;

  int deg = cnt[d]; deg = deg > MAXDEG ? MAXDEG : deg;
  if (t < deg) sid[t] = bucket[d * MAXDEG + t];
  if (t == deg) sid[deg] = d;                           // self loop (PyG appends it always)
  __syncthreads();
  int total = deg + 1;

  // per-head segment softmax: 8 heads x 8 lanes (wave 0)
  if (t < 64) {
    int hd = t >> 3, le = t & 7;
    float ard = ar[d * 8 + hd];
    float m = -1e30f;
    for (int e = le; e < total; e += 8) {
      float lg = al[sid[e] * 8 + hd] + ard;
      lg = lg > 0.f ? lg : 0.2f * lg;                   // leaky_relu(0.2)
      w[hd][e] = lg;
      m = fmaxf(m, lg);
    }
#pragma unroll
    for (int off = 4; off; off >>= 1) m = fmaxf(m, __shfl_xor(m, off));
    float den = 0.f;
    for (int e = le; e < total; e += 8) { float xv = expf(w[hd][e] - m); w[hd][e] = xv; den += xv; }
#pragma unroll
    for (int off = 4; off; off >>= 1) den += __shfl_xor(den, off);
    float inv = 1.f / den;
    for (int e = le; e < total; e += 8) w[hd][e] *= inv;
  }
  __syncthreads();

  // vectorized gather-accumulate: thread t owns dims [t*8, t*8+8) (one head each)
  int i0 = t * 8;
  float acc[8] = {0.f, 0.f, 0.f, 0.f, 0.f, 0.f, 0.f, 0.f};
  if (i0 < D) {
    int hd = i0 / C;
    const bf16* __restrict__ Hp = H + i0;
    for (int e = 0; e < total; ++e) {
      union { short8 v; short s[8]; } u;
      u.v = *(const short8*)&Hp[(size_t)sid[e] * D];
      float we = w[hd][e];
#pragma unroll
      for (int j = 0; j < 8; ++j) acc[j] = fmaf(we, bits2f(u.s[j]), acc[j]);
    }
  }

  if (concat) {
    float v[8];
    float s1 = 0.f, s2 = 0.f;
    if (i0 < D) {
#pragma unroll
      for (int j = 0; j < 8; ++j) {
        float vv = acc[j] + ldsel(bias, i0 + j, wF);
        vv = vv > 0.f ? vv : expf(vv) - 1.f;            // ELU
        v[j] = vv; s1 += vv; s2 += vv * vv;
      }
    }
#pragma unroll
    for (int off = 32; off; off >>= 1) { s1 += __shfl_down(s1, off); s2 += __shfl_down(s2, off); }
    if (lane == 0) { r1[wave] = s1; r2[wave] = s2; }
    __syncthreads();
    if (t == 0) {
      float S1 = r1[0] + r1[1] + r1[2] + r1[3];
      float S2 = r2[0] + r2[1] + r2[2] + r2[3];
      float mu = S1 / D;
      sMu = mu; sRs = rsqrtf(S2 / D - mu * mu + 1e-5f);
    }
    __syncthreads();
    if (i0 < D) {
      union { short8 v; short s[8]; } ou;
#pragma unroll
      for (int j = 0; j < 8; ++j)
        ou.s[j] = f2bits((v[j] - sMu) * sRs * ldsel(ls, i0 + j, wF) + ldsel(lb, i0 + j, wF));
      *(short8*)&Xout[(size_t)d * D + i0] = ou.v;
    }
  } else {
    if (i0 < D) {
#pragma unroll
      for (int j = 0; j < 8; ++j) vals[i0 + j] = acc[j];
    }
    __syncthreads();
    if (t < 64) {   // wave 0: mean over 8 heads -> 64 dims, ELU, LN over 64
      float v = 0.f;
#pragma unroll
      for (int h = 0; h < 8; ++h) v += vals[h * 64 + t];
      v = v * 0.125f + ldsel(bias, t, wF);
      v = v > 0.f ? v : expf(v) - 1.f;
      float s1 = v, s2 = v * v;
#pragma unroll
      for (int off = 32; off; off >>= 1) { s1 += __shfl_xor(s1, off); s2 += __shfl_xor(s2, off); }
      float mu = s1 * (1.f / 64.f);
      float var = s2 * (1.f / 64.f) - mu * mu;
      float rs = rsqrtf(var + 1e-5f);
      Xout[(size_t)d * 64 + t] = f2b((v - mu) * rs * ldsel(ls, t, wF) + ldsel(lb, t, wF));
    }
  }
}

// ---------------- projection (64->256) + LN + GELU(erf) + q ----------------
__global__ __launch_bounds__(256) void k_proj(const bf16* __restrict__ X3, const void* __restrict__ wp,
                                              const void* __restrict__ bp, const void* __restrict__ lsp,
                                              const void* __restrict__ lbp, const void* __restrict__ wq,
                                              const void* __restrict__ bq,
                                              float* __restrict__ q, void* __restrict__ dout,
                                              const int* __restrict__ flags) {
  int wF = flags[1], xF = flags[0];
  int n = blockIdx.x, t = threadIdx.x;
  int lane = t & 63, wave = t >> 6;
  __shared__ float xs[64];
  __shared__ float r1[4], r2[4];
  __shared__ float sMu, sRs;
  if (t < 64) xs[t] = b2f(X3[n * 64 + t]);
  __syncthreads();
  float y = ldsel(bp, t, wF);
#pragma unroll 8
  for (int k = 0; k < 64; ++k) y = fmaf(xs[k], ldsel(wp, k * 256 + t, wF), y);
  float s1 = y, s2 = y * y;
#pragma unroll
  for (int off = 32; off; off >>= 1) { s1 += __shfl_down(s1, off); s2 += __shfl_down(s2, off); }
  if (lane == 0) { r1[wave] = s1; r2[wave] = s2; }
  __syncthreads();
  if (t == 0) {
    float S1 = r1[0] + r1[1] + r1[2] + r1[3];
    float S2 = r2[0] + r2[1] + r2[2] + r2[3];
    float mu = S1 / 256.f;
    sMu = mu; sRs = rsqrtf(S2 / 256.f - mu * mu + 1e-5f);
  }
  __syncthreads();
  float v = (y - sMu) * sRs * ldsel(lsp, t, wF) + ldsel(lbp, t, wF);
  float g = 0.5f * v * (1.f + erff(v * 0.70710678118654752f));   // exact GELU
  stsel(dout, (size_t)NG * 256 + (size_t)n * 256 + t, g, xF);    // node_out
  float qv = g * ldsel(wq, t, wF);
#pragma unroll
  for (int off = 32; off; off >>= 1) qv += __shfl_down(qv, off);
  if (lane == 0) r1[wave] = qv;
  __syncthreads();
  if (t == 0) q[n] = r1[0] + r1[1] + r1[2] + r1[3] + ldsel(bq, 0, wF);
}

// ---------------- attention pooling per graph ----------------
__global__ __launch_bounds__(256) void k_pool(void* __restrict__ dout, const float* __restrict__ q,
                                              const int* __restrict__ flags) {
  int xF = flags[0];
  int b = blockIdx.x, t = threadIdx.x;
  __shared__ float es[NREG];
  __shared__ float sDen;
  if (t < NREG) es[t] = q[b * NREG + t];
  __syncthreads();
  if (t == 0) {
    float m = -1e30f;
    for (int i = 0; i < NREG; ++i) m = fmaxf(m, es[i]);
    float den = 0.f;
    for (int i = 0; i < NREG; ++i) { float e = expf(es[i] - m); es[i] = e; den += e; }
    sDen = den;
  }
  __syncthreads();
  float acc = 0.f;
  for (int i = 0; i < NREG; ++i)
    acc = fmaf(es[i], ldsel(dout, (size_t)NG * 256 + (size_t)(b * NREG + i) * 256 + t, xF), acc);
  stsel(dout, (size_t)b * 256 + t, acc / sDen, xF);
}

// ---------------- launcher ----------------
extern "C" void kernel_launch(void* const* d_in, const int* in_sizes, int n_in,
                              void* d_out, int out_size, void* d_ws, size_t ws_size,
                              hipStream_t stream) {
  const void* nf  = d_in[0];
  const int* src  = (const int*)d_in[1];
  const int* dst  = (const int*)d_in[2];
  const void *w0 = d_in[4],  *b0 = d_in[5],  *as0 = d_in[6], *ad0 = d_in[7],  *ls0 = d_in[8],  *lb0 = d_in[9];
  const void *w1 = d_in[10], *b1 = d_in[11], *as1 = d_in[12], *ad1 = d_in[13], *ls1 = d_in[14], *lb1 = d_in[15];
  const void *w2 = d_in[16], *b2 = d_in[17], *as2 = d_in[18], *ad2 = d_in[19], *ls2 = d_in[20], *lb2 = d_in[21];
  const void *wp = d_in[22], *bp = d_in[23], *lsp = d_in[24], *lbp = d_in[25], *wq = d_in[26], *bq = d_in[27];

  // workspace layout — TOTAL ~31.4 MB (same as passing R2 layout)
  int* flags  = (int*)d_ws;                       // 4 ints (16 B)
  float* al   = (float*)(flags + 4);              // NN*8 f32
  float* ar   = al + NN * 8;
  int* cnt    = (int*)(ar + NN * 8);              // NN
  int* bucket = cnt + NN;                         // NN*MAXDEG
  float* q    = (float*)(bucket + NN * MAXDEG);   // NN f32
  bf16* X     = (bf16*)(q + NN);                  // NN*2048 bf16 (16B-aligned)
  bf16* Hb    = X + (size_t)NN * 2048;            // NN*2048 bf16

  // dead-region reuse for bf16 staging buffers:
  bf16* X0  = X;                          // NN*256 bf16 input copy (dead after gemm0)
  bf16* wt0 = X + (1 << 20);              // 2048*256  (dead after gemm0; agg0 then overwrites X)
  bf16* wt1 = Hb + (size_t)NN * 1024;     // 1024*2048 in upper half of Hb (gemm1 writes lower half)
  bf16* wt2 = Hb + (size_t)NN * 512;      // 512*1024  above gemm2's output region

  // stage 0: dtype detect, edge buckets, input conversion
  k_detect<<<1, 256, 0, stream>>>(nf, w0, flags);
  k_zero<<<(NN + 255) / 256, 256, 0, stream>>>(cnt, NN);
  k_scatter<<<(NE + 255) / 256, 256, 0, stream>>>(src, dst, cnt, bucket, NE);
  k_tobf16<<<(NN * 256 + 255) / 256, 256, 0, stream>>>(nf, X0, NN * 256, flags, 0);

  // layer 0: 256 -> 8x256 concat (2048);  grid (2048/64)*(3712/64) = 32*58 = 1856
  k_transpose<<<dim3(256 / 32, 2048 / 32), 256, 0, stream>>>(w0, wt0, 256, 2048, flags);
  k_gemm_mfma<<<(2048 / 64) * (NN / 64), 256, 0, stream>>>(X0, wt0, Hb, NN, 2048, 256);
  k_attn<<<NN, 256, 0, stream>>>(Hb, as0, ad0, al, ar, 256, flags);
  k_agg<<<NN, 256, 0, stream>>>(Hb, al, ar, cnt, bucket, b0, ls0, lb0, X, 256, 1, flags);

  // layer 1: 2048 -> 8x128 concat (1024);  grid 16*58 = 928
  k_transpose<<<dim3(2048 / 32, 1024 / 32), 256, 0, stream>>>(w1, wt1, 2048, 1024, flags);
  k_gemm_mfma<<<(1024 / 64) * (NN / 64), 256, 0, stream>>>(X, wt1, Hb, NN, 1024, 2048);
  k_attn<<<NN, 256, 0, stream>>>(Hb, as1, ad1, al, ar, 128, flags);
  k_agg<<<NN, 256, 0, stream>>>(Hb, al, ar, cnt, bucket, b1, ls1, lb1, X, 128, 1, flags);

  // layer 2: 1024 -> 8x64 mean (64);  grid 8*58 = 464
  k_transpose<<<dim3(1024 / 32, 512 / 32), 256, 0, stream>>>(w2, wt2, 1024, 512, flags);
  k_gemm_mfma<<<(512 / 64) * (NN / 64), 256, 0, stream>>>(X, wt2, Hb, NN, 512, 1024);
  k_attn<<<NN, 256, 0, stream>>>(Hb, as2, ad2, al, ar, 64, flags);
  k_agg<<<NN, 256, 0, stream>>>(Hb, al, ar, cnt, bucket, b2, ls2, lb2, X, 64, 0, flags);

  // projection + GELU + q, then pooling (node_out lives in d_out)
  k_proj<<<NN, 256, 0, stream>>>(X, wp, bp, lsp, lbp, wq, bq, q, d_out, flags);
  k_pool<<<NG, 256, 0, stream>>>(d_out, q, flags);
}

// Round 5
// 386.155 us; speedup vs baseline: 1.0858x; 1.0026x over previous
//
#include <hip/hip_runtime.h>
#include <hip/hip_bf16.h>
#include <math.h>

typedef __hip_bfloat16 bf16;
typedef short short8 __attribute__((ext_vector_type(8)));
typedef float f32x4 __attribute__((ext_vector_type(4)));

__device__ __forceinline__ float b2f(const bf16 v) { return __bfloat162float(v); }
__device__ __forceinline__ bf16 f2b(const float v) { return __float2bfloat16(v); }

// raw-bits bf16 -> f32 (avoids struct round-trips on vector lanes)
__device__ __forceinline__ float bits2f(short s) {
  unsigned u = ((unsigned)(unsigned short)s) << 16;
  float f;
  __builtin_memcpy(&f, &u, 4);
  return f;
}
__device__ __forceinline__ short f2bits(float f) {
  bf16 b = f2b(f);
  short s;
  __builtin_memcpy(&s, &b, 2);
  return s;
}

// dtype-flexible load/store: f32 flag selects float32 vs bfloat16 interpretation
__device__ __forceinline__ float ldsel(const void* p, size_t i, int f32) {
  return f32 ? ((const float*)p)[i] : b2f(((const bf16*)p)[i]);
}
__device__ __forceinline__ void stsel(void* p, size_t i, float v, int f32) {
  if (f32) ((float*)p)[i] = v; else ((bf16*)p)[i] = f2b(v);
}

#define NN 3712          // nodes
#define NE 37120         // edges (without self loops)
#define NG 32            // graphs
#define NREG 116         // nodes per graph
#define MAXDEG 48        // bucket capacity (in-degree ~ Poisson(10); P(>48) ~ 1e-18)

// ---------------- dtype detector ----------------
__global__ __launch_bounds__(256) void k_detect(const void* nf, const void* w0, int* flags) {
  __shared__ int bad[2];
  if (threadIdx.x < 2) bad[threadIdx.x] = 0;
  __syncthreads();
  const bf16* a = (const bf16*)nf;
  const bf16* b = (const bf16*)w0;
  int l0 = 0, l1 = 0;
  for (int i = threadIdx.x; i < 4096; i += 256) {
    float x = b2f(a[i]); if (!(fabsf(x) < 1e4f)) l0++;
    float y = b2f(b[i]); if (!(fabsf(y) < 1e4f)) l1++;
  }
  if (l0) atomicAdd(&bad[0], l0);
  if (l1) atomicAdd(&bad[1], l1);
  __syncthreads();
  if (threadIdx.x == 0) { flags[0] = bad[0] > 0; flags[1] = bad[1] > 0; }
}

// ---------------- utility kernels ----------------
__global__ __launch_bounds__(256) void k_zero(int* __restrict__ p, int n) {
  int i = blockIdx.x * 256 + threadIdx.x;
  if (i < n) p[i] = 0;
}

__global__ __launch_bounds__(256) void k_scatter(const int* __restrict__ src, const int* __restrict__ dst,
                                                 int* __restrict__ cnt, int* __restrict__ bucket, int E) {
  int e = blockIdx.x * 256 + threadIdx.x;
  if (e < E) {
    int d = dst[e], s = src[e];
    if ((unsigned)d < NN && (unsigned)s < NN) {
      int p = atomicAdd(&cnt[d], 1);
      if (p < MAXDEG) bucket[d * MAXDEG + p] = s;
    }
  }
}

// convert (f32|bf16) -> bf16
__global__ __launch_bounds__(256) void k_tobf16(const void* __restrict__ in, bf16* __restrict__ out,
                                                int n, const int* __restrict__ flags, int fidx) {
  int f = flags[fidx];
  int i = blockIdx.x * 256 + threadIdx.x;
  if (i < n) out[i] = f2b(ldsel(in, i, f));
}

// transpose W[K][N] -> Wt[N][K], output bf16. K,N multiples of 32.
__global__ __launch_bounds__(256) void k_transpose(const void* __restrict__ W, bf16* __restrict__ Wt,
                                                   int K, int N, const int* __restrict__ flags) {
  int f = flags[1];
  __shared__ float tile[32][33];
  int tx = threadIdx.x & 31, ty = threadIdx.x >> 5;   // 32 x 8
  int k0 = blockIdx.x * 32, n0 = blockIdx.y * 32;
#pragma unroll
  for (int i = 0; i < 4; ++i)
    tile[ty + i * 8][tx] = ldsel(W, (size_t)(k0 + ty + i * 8) * N + n0 + tx, f);
  __syncthreads();
#pragma unroll
  for (int i = 0; i < 4; ++i)
    Wt[(size_t)(n0 + ty + i * 8) * K + k0 + tx] = f2b(tile[tx][ty + i * 8]);
}

// ---------------- MFMA bf16 NT GEMM: C[MxN] = A[MxK] * Bt[NxK]^T ----------------
// 64x64 tile, BK=64, 4 waves (2x2), each wave 2x2 tiles of 16x16x32 MFMA over 2 k-slices.
// (R3->R4 verified: occupancy-driven retile took gemm1 63.7us -> <56us.)
__global__ __launch_bounds__(256) void k_gemm_mfma(const bf16* __restrict__ A, const bf16* __restrict__ Bt,
                                                   bf16* __restrict__ C, int M, int N, int K) {
  __shared__ short As[64 * 72];
  __shared__ short Bs[64 * 72];
  int tid = threadIdx.x;
  int wave = tid >> 6, lane = tid & 63;
  int wr = wave >> 1, wc = wave & 1;
  int quad = lane >> 4, ml = lane & 15;

  int nbx = N >> 6;
  int total = gridDim.x;
  int id = blockIdx.x;
  // XCD-bijective chunk swizzle (valid when total % 8 == 0; all our grids are)
  int tile = ((total & 7) == 0) ? ((id & 7) * (total >> 3) + (id >> 3)) : id;
  int n0 = (tile % nbx) << 6;
  int m0 = (tile / nbx) << 6;

  f32x4 acc[2][2];
#pragma unroll
  for (int rt = 0; rt < 2; ++rt)
#pragma unroll
    for (int ct = 0; ct < 2; ++ct)
#pragma unroll
      for (int r = 0; r < 4; ++r) acc[rt][ct][r] = 0.f;

  for (int k0 = 0; k0 < K; k0 += 64) {
    __syncthreads();                       // previous-iter LDS reads done
#pragma unroll
    for (int i = 0; i < 2; ++i) {
      int c = tid + (i << 8);              // 512 16B-chunks per operand tile (64 rows x 8 chunks)
      int row = c >> 3, kg = (c & 7) << 3;
      *(uint4*)&As[row * 72 + kg] = *(const uint4*)&A[(size_t)(m0 + row) * K + k0 + kg];
      *(uint4*)&Bs[row * 72 + kg] = *(const uint4*)&Bt[(size_t)(n0 + row) * K + k0 + kg];
    }
    __syncthreads();
    short8 af[2][2], bfr[2][2];
#pragma unroll
    for (int rt = 0; rt < 2; ++rt)
#pragma unroll
      for (int kk = 0; kk < 2; ++kk)
        af[rt][kk] = *(const short8*)&As[(wr * 32 + rt * 16 + ml) * 72 + kk * 32 + quad * 8];
#pragma unroll
    for (int ct = 0; ct < 2; ++ct)
#pragma unroll
      for (int kk = 0; kk < 2; ++kk)
        bfr[ct][kk] = *(const short8*)&Bs[(wc * 32 + ct * 16 + ml) * 72 + kk * 32 + quad * 8];
#pragma unroll
    for (int rt = 0; rt < 2; ++rt)
#pragma unroll
      for (int ct = 0; ct < 2; ++ct)
#pragma unroll
        for (int kk = 0; kk < 2; ++kk)
          acc[rt][ct] = __builtin_amdgcn_mfma_f32_16x16x32_bf16(af[rt][kk], bfr[ct][kk], acc[rt][ct], 0, 0, 0);
  }
  // C/D layout (verified m89/m91): col = lane&15, row = quad*4 + reg
#pragma unroll
  for (int rt = 0; rt < 2; ++rt)
#pragma unroll
    for (int ct = 0; ct < 2; ++ct)
#pragma unroll
      for (int r = 0; r < 4; ++r) {
        int grow = m0 + wr * 32 + rt * 16 + quad * 4 + r;
        int gcol = n0 + wc * 32 + ct * 16 + ml;
        C[(size_t)grow * N + gcol] = f2b(acc[rt][ct][r]);
      }
}

// ---------------- attention coefficients al/ar: (N,8) ----------------
// Thread t owns 8 contiguous dims (short8 load); per-head group reduce via shfl_xor.
__global__ __launch_bounds__(256) void k_attn(const bf16* __restrict__ H, const void* __restrict__ a_s,
                                              const void* __restrict__ a_d, float* __restrict__ al,
                                              float* __restrict__ ar, int C, const int* __restrict__ flags) {
  int wF = flags[1];
  int n = blockIdx.x;
  int t = threadIdx.x;
  int D = 8 * C;
  int i0 = t * 8;
  if (i0 >= D) return;                     // no barriers below
  union { short8 v; short s[8]; } u;
  u.v = *(const short8*)&H[(size_t)n * D + i0];
  float ps = 0.f, pd = 0.f;
#pragma unroll
  for (int j = 0; j < 8; ++j) {
    float h = bits2f(u.s[j]);
    ps = fmaf(h, ldsel(a_s, i0 + j, wF), ps);
    pd = fmaf(h, ldsel(a_d, i0 + j, wF), pd);
  }
  int G = C >> 3;                          // lanes per head group: 32/16/8 (aligned pow2, within-wave)
  for (int off = G >> 1; off; off >>= 1) {
    ps += __shfl_xor(ps, off);
    pd += __shfl_xor(pd, off);
  }
  if ((t & (G - 1)) == 0) {
    int hd = i0 / C;
    al[n * 8 + hd] = ps;
    ar[n * 8 + hd] = pd;
  }
}

// ---------------- per-dst softmax + aggregation + bias + ELU + LayerNorm ----------------
// Launched with D/8 threads (256/128/64): every thread owns 8 dims, no idle lanes.
// R4 counters showed latency-bound (VALU 21%, HBM 5%, dur flat): fixes here are
// (a) all-wave register softmax (per-head G=C/8-lane groups, shfl_xor reduce),
// (b) 8-deep software-pipelined gather: neighbor list padded to x8, 8 short8 loads
//     issued back-to-back per chunk so L2 latency is amortized 8x.
__global__ void k_agg(const bf16* __restrict__ H, const float* __restrict__ al,
                      const float* __restrict__ ar, const int* __restrict__ cnt,
                      const int* __restrict__ bucket, const void* __restrict__ bias,
                      const void* __restrict__ ls, const void* __restrict__ lb,
                      bf16* __restrict__ Xout, int C, int concat,
                      const int* __restrict__ flags) {
  int wF = flags[1];
  // bijective node swizzle: XCD x = bid&7 handles graphs {x, x+8, x+16, x+24}
  int bid = blockIdx.x;
  int x = bid & 7, jj = bid >> 3;                       // jj in [0,464)
  int d = (x + ((jj / NREG) << 3)) * NREG + (jj % NREG);
  int t = threadIdx.x;
  int nt = blockDim.x;                                  // = D/8
  int lane = t & 63, wave = t >> 6;
  int D = 8 * C;
  __shared__ int sid[MAXDEG + 8];                       // padded to x8
  __shared__ float w[8][MAXDEG + 8];
  __shared__ float vals[512];                           // mean (non-concat) path only
  __shared__ float r1[4], r2[4];
  __shared__ float sMu, sRs;

  int deg = cnt[d]; deg = deg > MAXDEG ? MAXDEG : deg;
  int total = deg + 1;
  int padded = (total + 7) & ~7;                        // <= 56 <= nt for all layers
  if (t < deg) sid[t] = bucket[d * MAXDEG + t];
  else if (t < padded) sid[t] = d;                      // t==deg: self loop; t>deg: pad (w=0)
  __syncthreads();

  // all-wave register softmax: head hd's weights computed by its G-lane group
  int i0 = t * 8;
  int hd = i0 / C;                                      // this thread's head
  int G = C >> 3;                                       // lanes per head group (32/16/8)
  int gl = t & (G - 1);
  float ard = ar[d * 8 + hd];
  float m = -1e30f;
  for (int e = gl; e < total; e += G) {
    float lg = al[sid[e] * 8 + hd] + ard;
    lg = lg > 0.f ? lg : 0.2f * lg;                     // leaky_relu(0.2)
    w[hd][e] = lg;
    m = fmaxf(m, lg);
  }
  for (int off = G >> 1; off; off >>= 1) m = fmaxf(m, __shfl_xor(m, off));
  float den = 0.f;
  for (int e = gl; e < total; e += G) { float xv = expf(w[hd][e] - m); w[hd][e] = xv; den += xv; }
  for (int off = G >> 1; off; off >>= 1) den += __shfl_xor(den, off);
  float inv = 1.f / den;
  for (int e = gl; e < total; e += G) w[hd][e] *= inv;
  if (gl < padded - total) w[hd][total + gl] = 0.f;     // pad weights (padded-total < 8 <= G)
  // no barrier: w[hd][*] is written and read by the same G-lane group (within one wave)

  // 8-deep pipelined gather-accumulate: thread t owns dims [t*8, t*8+8)
  float acc[8] = {0.f, 0.f, 0.f, 0.f, 0.f, 0.f, 0.f, 0.f};
  const bf16* __restrict__ Hp = H + i0;
  for (int eb = 0; eb < padded; eb += 8) {
    short8 u[8];
#pragma unroll
    for (int j = 0; j < 8; ++j)
      u[j] = *(const short8*)&Hp[(size_t)sid[eb + j] * D];
#pragma unroll
    for (int j = 0; j < 8; ++j) {
      float we = w[hd][eb + j];
      union { short8 v; short s[8]; } uu; uu.v = u[j];
#pragma unroll
      for (int k = 0; k < 8; ++k) acc[k] = fmaf(we, bits2f(uu.s[k]), acc[k]);
    }
  }

  if (concat) {
    float v[8];
    float s1 = 0.f, s2 = 0.f;
#pragma unroll
    for (int j = 0; j < 8; ++j) {
      float vv = acc[j] + ldsel(bias, i0 + j, wF);
      vv = vv > 0.f ? vv : expf(vv) - 1.f;              // ELU
      v[j] = vv; s1 += vv; s2 += vv * vv;
    }
#pragma unroll
    for (int off = 32; off; off >>= 1) { s1 += __shfl_down(s1, off); s2 += __shfl_down(s2, off); }
    if (lane == 0) { r1[wave] = s1; r2[wave] = s2; }
    __syncthreads();
    if (t == 0) {
      float S1 = 0.f, S2 = 0.f;
      int nw = nt >> 6;
      for (int i = 0; i < nw; ++i) { S1 += r1[i]; S2 += r2[i]; }
      float mu = S1 / D;
      sMu = mu; sRs = rsqrtf(S2 / D - mu * mu + 1e-5f);
    }
    __syncthreads();
    union { short8 v; short s[8]; } ou;
#pragma unroll
    for (int j = 0; j < 8; ++j)
      ou.s[j] = f2bits((v[j] - sMu) * sRs * ldsel(ls, i0 + j, wF) + ldsel(lb, i0 + j, wF));
    *(short8*)&Xout[(size_t)d * D + i0] = ou.v;
  } else {
    // layer 2: nt=64, one wave; mean over 8 heads -> 64 dims, ELU, LN over 64
#pragma unroll
    for (int j = 0; j < 8; ++j) vals[i0 + j] = acc[j];
    __syncthreads();
    float v = 0.f;
#pragma unroll
    for (int h = 0; h < 8; ++h) v += vals[h * 64 + t];
    v = v * 0.125f + ldsel(bias, t, wF);
    v = v > 0.f ? v : expf(v) - 1.f;
    float s1 = v, s2 = v * v;
#pragma unroll
    for (int off = 32; off; off >>= 1) { s1 += __shfl_xor(s1, off); s2 += __shfl_xor(s2, off); }
    float mu = s1 * (1.f / 64.f);
    float var = s2 * (1.f / 64.f) - mu * mu;
    float rs = rsqrtf(var + 1e-5f);
    Xout[(size_t)d * 64 + t] = f2b((v - mu) * rs * ldsel(ls, t, wF) + ldsel(lb, t, wF));
  }
}

// ---------------- projection (64->256) + LN + GELU(erf) + q ----------------
__global__ __launch_bounds__(256) void k_proj(const bf16* __restrict__ X3, const void* __restrict__ wp,
                                              const void* __restrict__ bp, const void* __restrict__ lsp,
                                              const void* __restrict__ lbp, const void* __restrict__ wq,
                                              const void* __restrict__ bq,
                                              float* __restrict__ q, void* __restrict__ dout,
                                              const int* __restrict__ flags) {
  int wF = flags[1], xF = flags[0];
  int n = blockIdx.x, t = threadIdx.x;
  int lane = t & 63, wave = t >> 6;
  __shared__ float xs[64];
  __shared__ float r1[4], r2[4];
  __shared__ float sMu, sRs;
  if (t < 64) xs[t] = b2f(X3[n * 64 + t]);
  __syncthreads();
  float y = ldsel(bp, t, wF);
#pragma unroll 8
  for (int k = 0; k < 64; ++k) y = fmaf(xs[k], ldsel(wp, k * 256 + t, wF), y);
  float s1 = y, s2 = y * y;
#pragma unroll
  for (int off = 32; off; off >>= 1) { s1 += __shfl_down(s1, off); s2 += __shfl_down(s2, off); }
  if (lane == 0) { r1[wave] = s1; r2[wave] = s2; }
  __syncthreads();
  if (t == 0) {
    float S1 = r1[0] + r1[1] + r1[2] + r1[3];
    float S2 = r2[0] + r2[1] + r2[2] + r2[3];
    float mu = S1 / 256.f;
    sMu = mu; sRs = rsqrtf(S2 / 256.f - mu * mu + 1e-5f);
  }
  __syncthreads();
  float v = (y - sMu) * sRs * ldsel(lsp, t, wF) + ldsel(lbp, t, wF);
  float g = 0.5f * v * (1.f + erff(v * 0.70710678118654752f));   // exact GELU
  stsel(dout, (size_t)NG * 256 + (size_t)n * 256 + t, g, xF);    // node_out
  float qv = g * ldsel(wq, t, wF);
#pragma unroll
  for (int off = 32; off; off >>= 1) qv += __shfl_down(qv, off);
  if (lane == 0) r1[wave] = qv;
  __syncthreads();
  if (t == 0) q[n] = r1[0] + r1[1] + r1[2] + r1[3] + ldsel(bq, 0, wF);
}

// ---------------- attention pooling per graph ----------------
__global__ __launch_bounds__(256) void k_pool(void* __restrict__ dout, const float* __restrict__ q,
                                              const int* __restrict__ flags) {
  int xF = flags[0];
  int b = blockIdx.x, t = threadIdx.x;
  __shared__ float es[NREG];
  __shared__ float sDen;
  if (t < NREG) es[t] = q[b * NREG + t];
  __syncthreads();
  if (t == 0) {
    float m = -1e30f;
    for (int i = 0; i < NREG; ++i) m = fmaxf(m, es[i]);
    float den = 0.f;
    for (int i = 0; i < NREG; ++i) { float e = expf(es[i] - m); es[i] = e; den += e; }
    sDen = den;
  }
  __syncthreads();
  float acc = 0.f;
  for (int i = 0; i < NREG; ++i)
    acc = fmaf(es[i], ldsel(dout, (size_t)NG * 256 + (size_t)(b * NREG + i) * 256 + t, xF), acc);
  stsel(dout, (size_t)b * 256 + t, acc / sDen, xF);
}

// ---------------- launcher ----------------
extern "C" void kernel_launch(void* const* d_in, const int* in_sizes, int n_in,
                              void* d_out, int out_size, void* d_ws, size_t ws_size,
                              hipStream_t stream) {
  const void* nf  = d_in[0];
  const int* src  = (const int*)d_in[1];
  const int* dst  = (const int*)d_in[2];
  const void *w0 = d_in[4],  *b0 = d_in[5],  *as0 = d_in[6], *ad0 = d_in[7],  *ls0 = d_in[8],  *lb0 = d_in[9];
  const void *w1 = d_in[10], *b1 = d_in[11], *as1 = d_in[12], *ad1 = d_in[13], *ls1 = d_in[14], *lb1 = d_in[15];
  const void *w2 = d_in[16], *b2 = d_in[17], *as2 = d_in[18], *ad2 = d_in[19], *ls2 = d_in[20], *lb2 = d_in[21];
  const void *wp = d_in[22], *bp = d_in[23], *lsp = d_in[24], *lbp = d_in[25], *wq = d_in[26], *bq = d_in[27];

  // workspace layout — TOTAL ~31.4 MB (same as passing R2 layout)
  int* flags  = (int*)d_ws;                       // 4 ints (16 B)
  float* al   = (float*)(flags + 4);              // NN*8 f32
  float* ar   = al + NN * 8;
  int* cnt    = (int*)(ar + NN * 8);              // NN
  int* bucket = cnt + NN;                         // NN*MAXDEG
  float* q    = (float*)(bucket + NN * MAXDEG);   // NN f32
  bf16* X     = (bf16*)(q + NN);                  // NN*2048 bf16 (16B-aligned)
  bf16* Hb    = X + (size_t)NN * 2048;            // NN*2048 bf16

  // dead-region reuse for bf16 staging buffers:
  bf16* X0  = X;                          // NN*256 bf16 input copy (dead after gemm0)
  bf16* wt0 = X + (1 << 20);              // 2048*256  (dead after gemm0; agg0 then overwrites X)
  bf16* wt1 = Hb + (size_t)NN * 1024;     // 1024*2048 in upper half of Hb (gemm1 writes lower half)
  bf16* wt2 = Hb + (size_t)NN * 512;      // 512*1024  above gemm2's output region

  // stage 0: dtype detect, edge buckets, input conversion
  k_detect<<<1, 256, 0, stream>>>(nf, w0, flags);
  k_zero<<<(NN + 255) / 256, 256, 0, stream>>>(cnt, NN);
  k_scatter<<<(NE + 255) / 256, 256, 0, stream>>>(src, dst, cnt, bucket, NE);
  k_tobf16<<<(NN * 256 + 255) / 256, 256, 0, stream>>>(nf, X0, NN * 256, flags, 0);

  // layer 0: 256 -> 8x256 concat (2048);  gemm grid (2048/64)*(3712/64) = 1856
  k_transpose<<<dim3(256 / 32, 2048 / 32), 256, 0, stream>>>(w0, wt0, 256, 2048, flags);
  k_gemm_mfma<<<(2048 / 64) * (NN / 64), 256, 0, stream>>>(X0, wt0, Hb, NN, 2048, 256);
  k_attn<<<NN, 256, 0, stream>>>(Hb, as0, ad0, al, ar, 256, flags);
  k_agg<<<NN, 256, 0, stream>>>(Hb, al, ar, cnt, bucket, b0, ls0, lb0, X, 256, 1, flags);

  // layer 1: 2048 -> 8x128 concat (1024);  gemm grid 928; agg block 128
  k_transpose<<<dim3(2048 / 32, 1024 / 32), 256, 0, stream>>>(w1, wt1, 2048, 1024, flags);
  k_gemm_mfma<<<(1024 / 64) * (NN / 64), 256, 0, stream>>>(X, wt1, Hb, NN, 1024, 2048);
  k_attn<<<NN, 128, 0, stream>>>(Hb, as1, ad1, al, ar, 128, flags);
  k_agg<<<NN, 128, 0, stream>>>(Hb, al, ar, cnt, bucket, b1, ls1, lb1, X, 128, 1, flags);

  // layer 2: 1024 -> 8x64 mean (64);  gemm grid 464; agg block 64
  k_transpose<<<dim3(1024 / 32, 512 / 32), 256, 0, stream>>>(w2, wt2, 1024, 512, flags);
  k_gemm_mfma<<<(512 / 64) * (NN / 64), 256, 0, stream>>>(X, wt2, Hb, NN, 512, 1024);
  k_attn<<<NN, 64, 0, stream>>>(Hb, as2, ad2, al, ar, 64, flags);
  k_agg<<<NN, 64, 0, stream>>>(Hb, al, ar, cnt, bucket, b2, ls2, lb2, X, 64, 0, flags);

  // projection + GELU + q, then pooling (node_out lives in d_out)
  k_proj<<<NN, 256, 0, stream>>>(X, wp, bp, lsp, lbp, wq, bq, q, d_out, flags);
  k_pool<<<NG, 256, 0, stream>>>(d_out, q, flags);
}

// Round 6
// 366.761 us; speedup vs baseline: 1.1433x; 1.0529x over previous
//
#include <hip/hip_runtime.h>
#include <hip/hip_bf16.h>
#include <math.h>

typedef __hip_bfloat16 bf16;
typedef short short8 __attribute__((ext_vector_type(8)));
typedef float f32x4 __attribute__((ext_vector_type(4)));

__device__ __forceinline__ float b2f(const bf16 v) { return __bfloat162float(v); }
__device__ __forceinline__ bf16 f2b(const float v) { return __float2bfloat16(v); }

// raw-bits bf16 -> f32
__device__ __forceinline__ float bits2f(short s) {
  unsigned u = ((unsigned)(unsigned short)s) << 16;
  float f;
  __builtin_memcpy(&f, &u, 4);
  return f;
}
__device__ __forceinline__ short f2bits(float f) {
  bf16 b = f2b(f);
  short s;
  __builtin_memcpy(&s, &b, 2);
  return s;
}

// dtype-flexible load/store: f32 flag selects float32 vs bfloat16 interpretation
__device__ __forceinline__ float ldsel(const void* p, size_t i, int f32) {
  return f32 ? ((const float*)p)[i] : b2f(((const bf16*)p)[i]);
}
__device__ __forceinline__ void stsel(void* p, size_t i, float v, int f32) {
  if (f32) ((float*)p)[i] = v; else ((bf16*)p)[i] = f2b(v);
}

#define NN 3712          // nodes
#define NE 37120         // edges (without self loops)
#define NG 32            // graphs
#define NREG 116         // nodes per graph
#define MAXDEG 48        // bucket capacity

// ---------------- dtype detector ----------------
__global__ __launch_bounds__(256) void k_detect(const void* nf, const void* w0, int* flags) {
  __shared__ int bad[2];
  if (threadIdx.x < 2) bad[threadIdx.x] = 0;
  __syncthreads();
  const bf16* a = (const bf16*)nf;
  const bf16* b = (const bf16*)w0;
  int l0 = 0, l1 = 0;
  for (int i = threadIdx.x; i < 4096; i += 256) {
    float x = b2f(a[i]); if (!(fabsf(x) < 1e4f)) l0++;
    float y = b2f(b[i]); if (!(fabsf(y) < 1e4f)) l1++;
  }
  if (l0) atomicAdd(&bad[0], l0);
  if (l1) atomicAdd(&bad[1], l1);
  __syncthreads();
  if (threadIdx.x == 0) { flags[0] = bad[0] > 0; flags[1] = bad[1] > 0; }
}

// ---------------- utility kernels ----------------
__global__ __launch_bounds__(256) void k_zero(int* __restrict__ p, int n) {
  int i = blockIdx.x * 256 + threadIdx.x;
  if (i < n) p[i] = 0;
}

__global__ __launch_bounds__(256) void k_scatter(const int* __restrict__ src, const int* __restrict__ dst,
                                                 int* __restrict__ cnt, int* __restrict__ bucket, int E) {
  int e = blockIdx.x * 256 + threadIdx.x;
  if (e < E) {
    int d = dst[e], s = src[e];
    if ((unsigned)d < NN && (unsigned)s < NN) {
      int p = atomicAdd(&cnt[d], 1);
      if (p < MAXDEG) bucket[d * MAXDEG + p] = s;
    }
  }
}

// convert (f32|bf16) -> bf16
__global__ __launch_bounds__(256) void k_tobf16(const void* __restrict__ in, bf16* __restrict__ out,
                                                int n, const int* __restrict__ flags, int fidx) {
  int f = flags[fidx];
  int i = blockIdx.x * 256 + threadIdx.x;
  if (i < n) out[i] = f2b(ldsel(in, i, f));
}

// transpose W[K][N] -> Wt[N][K], output bf16. K,N multiples of 32.
__global__ __launch_bounds__(256) void k_transpose(const void* __restrict__ W, bf16* __restrict__ Wt,
                                                   int K, int N, const int* __restrict__ flags) {
  int f = flags[1];
  __shared__ float tile[32][33];
  int tx = threadIdx.x & 31, ty = threadIdx.x >> 5;   // 32 x 8
  int k0 = blockIdx.x * 32, n0 = blockIdx.y * 32;
#pragma unroll
  for (int i = 0; i < 4; ++i)
    tile[ty + i * 8][tx] = ldsel(W, (size_t)(k0 + ty + i * 8) * N + n0 + tx, f);
  __syncthreads();
#pragma unroll
  for (int i = 0; i < 4; ++i)
    Wt[(size_t)(n0 + ty + i * 8) * K + k0 + tx] = f2b(tile[tx][ty + i * 8]);
}

// ---------------- MFMA bf16 NT GEMM: C[MxN] = A[MxK] * Bt[NxK]^T ----------------
// 64x64 tile, BK=64, 4 waves (2x2). (R3->R4 verified: retile 63.7us -> <56us.)
__global__ __launch_bounds__(256) void k_gemm_mfma(const bf16* __restrict__ A, const bf16* __restrict__ Bt,
                                                   bf16* __restrict__ C, int M, int N, int K) {
  __shared__ short As[64 * 72];
  __shared__ short Bs[64 * 72];
  int tid = threadIdx.x;
  int wave = tid >> 6, lane = tid & 63;
  int wr = wave >> 1, wc = wave & 1;
  int quad = lane >> 4, ml = lane & 15;

  int nbx = N >> 6;
  int total = gridDim.x;
  int id = blockIdx.x;
  int tile = ((total & 7) == 0) ? ((id & 7) * (total >> 3) + (id >> 3)) : id;
  int n0 = (tile % nbx) << 6;
  int m0 = (tile / nbx) << 6;

  f32x4 acc[2][2];
#pragma unroll
  for (int rt = 0; rt < 2; ++rt)
#pragma unroll
    for (int ct = 0; ct < 2; ++ct)
#pragma unroll
      for (int r = 0; r < 4; ++r) acc[rt][ct][r] = 0.f;

  for (int k0 = 0; k0 < K; k0 += 64) {
    __syncthreads();
#pragma unroll
    for (int i = 0; i < 2; ++i) {
      int c = tid + (i << 8);
      int row = c >> 3, kg = (c & 7) << 3;
      *(uint4*)&As[row * 72 + kg] = *(const uint4*)&A[(size_t)(m0 + row) * K + k0 + kg];
      *(uint4*)&Bs[row * 72 + kg] = *(const uint4*)&Bt[(size_t)(n0 + row) * K + k0 + kg];
    }
    __syncthreads();
    short8 af[2][2], bfr[2][2];
#pragma unroll
    for (int rt = 0; rt < 2; ++rt)
#pragma unroll
      for (int kk = 0; kk < 2; ++kk)
        af[rt][kk] = *(const short8*)&As[(wr * 32 + rt * 16 + ml) * 72 + kk * 32 + quad * 8];
#pragma unroll
    for (int ct = 0; ct < 2; ++ct)
#pragma unroll
      for (int kk = 0; kk < 2; ++kk)
        bfr[ct][kk] = *(const short8*)&Bs[(wc * 32 + ct * 16 + ml) * 72 + kk * 32 + quad * 8];
#pragma unroll
    for (int rt = 0; rt < 2; ++rt)
#pragma unroll
      for (int ct = 0; ct < 2; ++ct)
#pragma unroll
        for (int kk = 0; kk < 2; ++kk)
          acc[rt][ct] = __builtin_amdgcn_mfma_f32_16x16x32_bf16(af[rt][kk], bfr[ct][kk], acc[rt][ct], 0, 0, 0);
  }
#pragma unroll
  for (int rt = 0; rt < 2; ++rt)
#pragma unroll
    for (int ct = 0; ct < 2; ++ct)
#pragma unroll
      for (int r = 0; r < 4; ++r) {
        int grow = m0 + wr * 32 + rt * 16 + quad * 4 + r;
        int gcol = n0 + wc * 32 + ct * 16 + ml;
        C[(size_t)grow * N + gcol] = f2b(acc[rt][ct][r]);
      }
}

// ---------------- attention coefficients al/ar: (N,8), 8 nodes per block ----------------
// a_src/a_dst hoisted to registers once, reused for 8 nodes; independent iterations give ILP.
__global__ void k_attn(const bf16* __restrict__ H, const void* __restrict__ a_s,
                       const void* __restrict__ a_d, float* __restrict__ al,
                       float* __restrict__ ar, int C, const int* __restrict__ flags) {
  int wF = flags[1];
  int t = threadIdx.x;                     // blockDim = D/8
  int D = 8 * C;
  int i0 = t * 8;
  float as8[8], ad8[8];
#pragma unroll
  for (int j = 0; j < 8; ++j) { as8[j] = ldsel(a_s, i0 + j, wF); ad8[j] = ldsel(a_d, i0 + j, wF); }
  int G = C >> 3;                          // lanes per head group (32/16/8)
  int hd = i0 / C;
  for (int it = 0; it < 8; ++it) {
    int n = blockIdx.x * 8 + it;
    union { short8 v; short s[8]; } u;
    u.v = *(const short8*)&H[(size_t)n * D + i0];
    float ps = 0.f, pd = 0.f;
#pragma unroll
    for (int j = 0; j < 8; ++j) {
      float h = bits2f(u.s[j]);
      ps = fmaf(h, as8[j], ps);
      pd = fmaf(h, ad8[j], pd);
    }
    for (int off = G >> 1; off; off >>= 1) {
      ps += __shfl_xor(ps, off);
      pd += __shfl_xor(pd, off);
    }
    if ((t & (G - 1)) == 0) {
      al[n * 8 + hd] = ps;
      ar[n * 8 + hd] = pd;
    }
  }
}

// ---------------- per-(dst,head) softmax max & 1/denominator ----------------
// 4 dsts per block (64 lanes each: 8 heads x 8 edge-lanes). Registerized, no LDS, no barriers.
__global__ __launch_bounds__(256) void k_edgew(const float* __restrict__ al, const float* __restrict__ ar,
                                               const int* __restrict__ cnt, const int* __restrict__ bucket,
                                               float* __restrict__ mbuf, float* __restrict__ ibuf) {
  int t = threadIdx.x;
  int q = t >> 6, l = t & 63, hd = l >> 3, el = l & 7;
  int d = blockIdx.x * 4 + q;                            // NN = 4*928
  int deg = cnt[d]; deg = deg > MAXDEG ? MAXDEG : deg;
  int total = deg + 1;
  float ard = ar[d * 8 + hd];
  float lgv[7];
  float m = -1e30f;
#pragma unroll
  for (int k = 0; k < 7; ++k) {
    int e = el + k * 8;
    float lg = -1e30f;
    if (e < total) {
      int s = e < deg ? bucket[d * MAXDEG + e] : d;      // self loop at e==deg
      lg = al[s * 8 + hd] + ard;
      lg = lg > 0.f ? lg : 0.2f * lg;                    // leaky_relu(0.2)
    }
    lgv[k] = lg;
    m = fmaxf(m, lg);
  }
#pragma unroll
  for (int off = 4; off; off >>= 1) m = fmaxf(m, __shfl_xor(m, off));
  float den = 0.f;
#pragma unroll
  for (int k = 0; k < 7; ++k) den += (lgv[k] > -1e29f) ? expf(lgv[k] - m) : 0.f;
#pragma unroll
  for (int off = 4; off; off >>= 1) den += __shfl_xor(den, off);
  if (el == 0) { mbuf[d * 8 + hd] = m; ibuf[d * 8 + hd] = 1.f / den; }
}

// ---------------- gather-aggregate + bias + ELU + LayerNorm ----------------
// Softmax stats precomputed (k_edgew); weight computed inline per edge (al load rides
// alongside the 16B H load). Pad-to-4 (12% waste). blockDim = D/8; barriers: 3.
__global__ void k_agg(const bf16* __restrict__ H, const float* __restrict__ al,
                      const float* __restrict__ ar, const float* __restrict__ mbuf,
                      const float* __restrict__ ibuf, const int* __restrict__ cnt,
                      const int* __restrict__ bucket, const void* __restrict__ bias,
                      const void* __restrict__ ls, const void* __restrict__ lb,
                      bf16* __restrict__ Xout, int C, int concat,
                      const int* __restrict__ flags) {
  int wF = flags[1];
  // bijective node swizzle: XCD x = bid&7 handles graphs {x, x+8, x+16, x+24}
  int bid = blockIdx.x;
  int x = bid & 7, jj = bid >> 3;
  int d = (x + ((jj / NREG) << 3)) * NREG + (jj % NREG);
  int t = threadIdx.x;
  int nt = blockDim.x;                                  // = D/8
  int lane = t & 63, wave = t >> 6;
  int D = 8 * C;
  __shared__ int sid[MAXDEG + 4];
  __shared__ float vals[512];                           // mean (non-concat) path only
  __shared__ float r1[4], r2[4];
  __shared__ float sMu, sRs;

  int deg = cnt[d]; deg = deg > MAXDEG ? MAXDEG : deg;
  int total = deg + 1;
  int padded = (total + 3) & ~3;                        // <= 52 <= nt for all layers
  if (t < padded) sid[t] = t < deg ? bucket[d * MAXDEG + t] : d;
  __syncthreads();

  int i0 = t * 8;
  int hd = i0 / C;
  float m = mbuf[d * 8 + hd], inv = ibuf[d * 8 + hd], ard = ar[d * 8 + hd];

  float acc[8] = {0.f, 0.f, 0.f, 0.f, 0.f, 0.f, 0.f, 0.f};
  const bf16* __restrict__ Hp = H + i0;
  for (int eb = 0; eb < padded; eb += 4) {
    int s4[4]; float a4[4]; short8 u4[4];
#pragma unroll
    for (int j = 0; j < 4; ++j) s4[j] = sid[eb + j];
#pragma unroll
    for (int j = 0; j < 4; ++j) {
      a4[j] = al[s4[j] * 8 + hd];
      u4[j] = *(const short8*)&Hp[(size_t)s4[j] * D];
    }
#pragma unroll
    for (int j = 0; j < 4; ++j) {
      float lg = a4[j] + ard;
      lg = lg > 0.f ? lg : 0.2f * lg;                   // leaky_relu(0.2)
      float we = (eb + j) < total ? expf(lg - m) * inv : 0.f;
      union { short8 v; short s[8]; } uu; uu.v = u4[j];
#pragma unroll
      for (int k2 = 0; k2 < 8; ++k2) acc[k2] = fmaf(we, bits2f(uu.s[k2]), acc[k2]);
    }
  }

  if (concat) {
    float v[8];
    float s1 = 0.f, s2 = 0.f;
#pragma unroll
    for (int j = 0; j < 8; ++j) {
      float vv = acc[j] + ldsel(bias, i0 + j, wF);
      vv = vv > 0.f ? vv : expf(vv) - 1.f;              // ELU
      v[j] = vv; s1 += vv; s2 += vv * vv;
    }
#pragma unroll
    for (int off = 32; off; off >>= 1) { s1 += __shfl_down(s1, off); s2 += __shfl_down(s2, off); }
    if (lane == 0) { r1[wave] = s1; r2[wave] = s2; }
    __syncthreads();
    if (t == 0) {
      float S1 = 0.f, S2 = 0.f;
      int nw = nt >> 6;
      for (int i = 0; i < nw; ++i) { S1 += r1[i]; S2 += r2[i]; }
      float mu = S1 / D;
      sMu = mu; sRs = rsqrtf(S2 / D - mu * mu + 1e-5f);
    }
    __syncthreads();
    union { short8 v; short s[8]; } ou;
#pragma unroll
    for (int j = 0; j < 8; ++j)
      ou.s[j] = f2bits((v[j] - sMu) * sRs * ldsel(ls, i0 + j, wF) + ldsel(lb, i0 + j, wF));
    *(short8*)&Xout[(size_t)d * D + i0] = ou.v;
  } else {
    // layer 2: nt=64, one wave; mean over 8 heads -> 64 dims, ELU, LN over 64
#pragma unroll
    for (int j = 0; j < 8; ++j) vals[i0 + j] = acc[j];
    __syncthreads();
    float v = 0.f;
#pragma unroll
    for (int h = 0; h < 8; ++h) v += vals[h * 64 + t];
    v = v * 0.125f + ldsel(bias, t, wF);
    v = v > 0.f ? v : expf(v) - 1.f;
    float s1 = v, s2 = v * v;
#pragma unroll
    for (int off = 32; off; off >>= 1) { s1 += __shfl_xor(s1, off); s2 += __shfl_xor(s2, off); }
    float mu = s1 * (1.f / 64.f);
    float var = s2 * (1.f / 64.f) - mu * mu;
    float rs = rsqrtf(var + 1e-5f);
    Xout[(size_t)d * 64 + t] = f2b((v - mu) * rs * ldsel(ls, t, wF) + ldsel(lb, t, wF));
  }
}

// ---------------- projection (64->256) + LN + GELU(erf) + q ----------------
__global__ __launch_bounds__(256) void k_proj(const bf16* __restrict__ X3, const void* __restrict__ wp,
                                              const void* __restrict__ bp, const void* __restrict__ lsp,
                                              const void* __restrict__ lbp, const void* __restrict__ wq,
                                              const void* __restrict__ bq,
                                              float* __restrict__ q, void* __restrict__ dout,
                                              const int* __restrict__ flags) {
  int wF = flags[1], xF = flags[0];
  int n = blockIdx.x, t = threadIdx.x;
  int lane = t & 63, wave = t >> 6;
  __shared__ float xs[64];
  __shared__ float r1[4], r2[4];
  __shared__ float sMu, sRs;
  if (t < 64) xs[t] = b2f(X3[n * 64 + t]);
  __syncthreads();
  float y = ldsel(bp, t, wF);
#pragma unroll 8
  for (int k = 0; k < 64; ++k) y = fmaf(xs[k], ldsel(wp, k * 256 + t, wF), y);
  float s1 = y, s2 = y * y;
#pragma unroll
  for (int off = 32; off; off >>= 1) { s1 += __shfl_down(s1, off); s2 += __shfl_down(s2, off); }
  if (lane == 0) { r1[wave] = s1; r2[wave] = s2; }
  __syncthreads();
  if (t == 0) {
    float S1 = r1[0] + r1[1] + r1[2] + r1[3];
    float S2 = r2[0] + r2[1] + r2[2] + r2[3];
    float mu = S1 / 256.f;
    sMu = mu; sRs = rsqrtf(S2 / 256.f - mu * mu + 1e-5f);
  }
  __syncthreads();
  float v = (y - sMu) * sRs * ldsel(lsp, t, wF) + ldsel(lbp, t, wF);
  float g = 0.5f * v * (1.f + erff(v * 0.70710678118654752f));   // exact GELU
  stsel(dout, (size_t)NG * 256 + (size_t)n * 256 + t, g, xF);    // node_out
  float qv = g * ldsel(wq, t, wF);
#pragma unroll
  for (int off = 32; off; off >>= 1) qv += __shfl_down(qv, off);
  if (lane == 0) r1[wave] = qv;
  __syncthreads();
  if (t == 0) q[n] = r1[0] + r1[1] + r1[2] + r1[3] + ldsel(bq, 0, wF);
}

// ---------------- attention pooling per graph ----------------
__global__ __launch_bounds__(256) void k_pool(void* __restrict__ dout, const float* __restrict__ q,
                                              const int* __restrict__ flags) {
  int xF = flags[0];
  int b = blockIdx.x, t = threadIdx.x;
  __shared__ float es[NREG];
  __shared__ float sDen;
  if (t < NREG) es[t] = q[b * NREG + t];
  __syncthreads();
  if (t == 0) {
    float m = -1e30f;
    for (int i = 0; i < NREG; ++i) m = fmaxf(m, es[i]);
    float den = 0.f;
    for (int i = 0; i < NREG; ++i) { float e = expf(es[i] - m); es[i] = e; den += e; }
    sDen = den;
  }
  __syncthreads();
  float acc = 0.f;
  for (int i = 0; i < NREG; ++i)
    acc = fmaf(es[i], ldsel(dout, (size_t)NG * 256 + (size_t)(b * NREG + i) * 256 + t, xF), acc);
  stsel(dout, (size_t)b * 256 + t, acc / sDen, xF);
}

// ---------------- launcher ----------------
extern "C" void kernel_launch(void* const* d_in, const int* in_sizes, int n_in,
                              void* d_out, int out_size, void* d_ws, size_t ws_size,
                              hipStream_t stream) {
  const void* nf  = d_in[0];
  const int* src  = (const int*)d_in[1];
  const int* dst  = (const int*)d_in[2];
  const void *w0 = d_in[4],  *b0 = d_in[5],  *as0 = d_in[6], *ad0 = d_in[7],  *ls0 = d_in[8],  *lb0 = d_in[9];
  const void *w1 = d_in[10], *b1 = d_in[11], *as1 = d_in[12], *ad1 = d_in[13], *ls1 = d_in[14], *lb1 = d_in[15];
  const void *w2 = d_in[16], *b2 = d_in[17], *as2 = d_in[18], *ad2 = d_in[19], *ls2 = d_in[20], *lb2 = d_in[21];
  const void *wp = d_in[22], *bp = d_in[23], *lsp = d_in[24], *lbp = d_in[25], *wq = d_in[26], *bq = d_in[27];

  // workspace layout (unchanged)
  int* flags  = (int*)d_ws;
  float* al   = (float*)(flags + 4);
  float* ar   = al + NN * 8;
  int* cnt    = (int*)(ar + NN * 8);
  int* bucket = cnt + NN;
  float* q    = (float*)(bucket + NN * MAXDEG);
  bf16* X     = (bf16*)(q + NN);
  bf16* Hb    = X + (size_t)NN * 2048;

  // softmax-stat scratch lives in the (currently dead) node_out region of d_out:
  // 237 KB used; k_proj fully overwrites node_out afterwards.
  float* mbuf = (float*)d_out;
  float* ibuf = mbuf + NN * 8;

  // dead-region reuse for bf16 staging buffers:
  bf16* X0  = X;
  bf16* wt0 = X + (1 << 20);
  bf16* wt1 = Hb + (size_t)NN * 1024;
  bf16* wt2 = Hb + (size_t)NN * 512;

  // stage 0
  k_detect<<<1, 256, 0, stream>>>(nf, w0, flags);
  k_zero<<<(NN + 255) / 256, 256, 0, stream>>>(cnt, NN);
  k_scatter<<<(NE + 255) / 256, 256, 0, stream>>>(src, dst, cnt, bucket, NE);
  k_tobf16<<<(NN * 256 + 255) / 256, 256, 0, stream>>>(nf, X0, NN * 256, flags, 0);

  // layer 0: 256 -> 8x256 concat (2048)
  k_transpose<<<dim3(256 / 32, 2048 / 32), 256, 0, stream>>>(w0, wt0, 256, 2048, flags);
  k_gemm_mfma<<<(2048 / 64) * (NN / 64), 256, 0, stream>>>(X0, wt0, Hb, NN, 2048, 256);
  k_attn<<<NN / 8, 256, 0, stream>>>(Hb, as0, ad0, al, ar, 256, flags);
  k_edgew<<<NN / 4, 256, 0, stream>>>(al, ar, cnt, bucket, mbuf, ibuf);
  k_agg<<<NN, 256, 0, stream>>>(Hb, al, ar, mbuf, ibuf, cnt, bucket, b0, ls0, lb0, X, 256, 1, flags);

  // layer 1: 2048 -> 8x128 concat (1024)
  k_transpose<<<dim3(2048 / 32, 1024 / 32), 256, 0, stream>>>(w1, wt1, 2048, 1024, flags);
  k_gemm_mfma<<<(1024 / 64) * (NN / 64), 256, 0, stream>>>(X, wt1, Hb, NN, 1024, 2048);
  k_attn<<<NN / 8, 128, 0, stream>>>(Hb, as1, ad1, al, ar, 128, flags);
  k_edgew<<<NN / 4, 256, 0, stream>>>(al, ar, cnt, bucket, mbuf, ibuf);
  k_agg<<<NN, 128, 0, stream>>>(Hb, al, ar, mbuf, ibuf, cnt, bucket, b1, ls1, lb1, X, 128, 1, flags);

  // layer 2: 1024 -> 8x64 mean (64)
  k_transpose<<<dim3(1024 / 32, 512 / 32), 256, 0, stream>>>(w2, wt2, 1024, 512, flags);
  k_gemm_mfma<<<(512 / 64) * (NN / 64), 256, 0, stream>>>(X, wt2, Hb, NN, 512, 1024);
  k_attn<<<NN / 8, 64, 0, stream>>>(Hb, as2, ad2, al, ar, 64, flags);
  k_edgew<<<NN / 4, 256, 0, stream>>>(al, ar, cnt, bucket, mbuf, ibuf);
  k_agg<<<NN, 64, 0, stream>>>(Hb, al, ar, mbuf, ibuf, cnt, bucket, b2, ls2, lb2, X, 64, 0, flags);

  // projection + GELU + q, then pooling (node_out lives in d_out)
  k_proj<<<NN, 256, 0, stream>>>(X, wp, bp, lsp, lbp, wq, bq, q, d_out, flags);
  k_pool<<<NG, 256, 0, stream>>>(d_out, q, flags);
}